// Round 6
// baseline (505.873 us; speedup 1.0000x reference)
//
#include <hip/hip_runtime.h>

typedef unsigned short u16;
typedef unsigned int   u32;
typedef __attribute__((ext_vector_type(8))) short v8s;   // 8 bf16 = 4 VGPRs
typedef __attribute__((ext_vector_type(4))) float v4f;   // MFMA accumulator / float4
typedef __attribute__((ext_vector_type(4))) float f4;

#define HID  128
#define TM   64      // edges per block (4 waves x 16 edges, waves independent)
#define ENCS 68      // enc/H transpose buffer row stride in u32 (16B-aligned, bank-spread)
#define OUTS 132     // out staging row stride in f32 (16B-aligned)

__device__ __forceinline__ u16 f2b(float f) {            // fp32 -> bf16 RNE
    union { float f; unsigned u; } v; v.f = f;
    unsigned u = v.u;
    u += 0x7fffu + ((u >> 16) & 1u);
    return (u16)(u >> 16);
}
__device__ __forceinline__ u32 pk2(float a, float b) {   // pack 2 bf16 into u32
    return (u32)f2b(a) | ((u32)f2b(b) << 16);
}

#define MFMA(A, B, C) __builtin_amdgcn_mfma_f32_16x16x32_bf16(A, B, C, 0, 0, 0)

// ---- weight fp32 -> bf16 pre-pass (once per launch, ~0.2 MB total) ----
// ws layout (u16 elems): Wp @0 (16384) | Wc @16384 | W1 @32768 (49152) | W2 @81920
__global__ void cvt_weights(const float* __restrict__ Wp, const float* __restrict__ Wc,
                            const float* __restrict__ W1, const float* __restrict__ W2,
                            u16* __restrict__ dst)
{
    int i = blockIdx.x * 256 + threadIdx.x;   // float4 index, 24576 total
    const float* s; int off;
    if (i < 4096)       { s = Wp; off = 0; }
    else if (i < 8192)  { s = Wc; off = 4096; }
    else if (i < 20480) { s = W1; off = 8192; }
    else                { s = W2; off = 20480; }
    int j = i - off;
    f4 v = ((const f4*)s)[j];
    u16* d = dst + (size_t)i * 4;
    d[0] = f2b(v[0]); d[1] = f2b(v[1]); d[2] = f2b(v[2]); d[3] = f2b(v[3]);
}

// Wave-private dataflow, ZERO barriers.
// Each wave: 16 edges x full 128-wide pipeline. Swapped-operand MFMA:
//   mfma(W_frag, X_frag) -> C[row=outfeat, col=edge(lane&15)]
// so stage outputs are already edge-per-lane; the quad-major->kchunk-major
// feature reshuffle is a wave-private LDS bounce (lgkm-ordered, no s_barrier).
__global__ __launch_bounds__(256, 3) void edge_attr_kernel(
    const float* __restrict__ x_src, const float* __restrict__ x_dst,
    const int* __restrict__ ei,
    const u16* __restrict__ wsW,                 // converted weights in d_ws
    const float* __restrict__ bp, const float* __restrict__ bc,
    const float* __restrict__ b1, const float* __restrict__ b2,
    float* __restrict__ out, int E)
{
    __shared__ __align__(16) u32 sT[4][2112];    // 8448 B per wave, 33792 B total

    const u16* wsWp = wsW;
    const u16* wsWc = wsW + 16384;
    const u16* wsW1 = wsW + 32768;
    const u16* wsW2 = wsW + 81920;

    const int t    = threadIdx.x;
    const int w    = t >> 6;        // wave 0..3
    const int lane = t & 63;
    const int ln   = lane & 15;     // edge-within-wave AND weight-row selector
    const int lq   = lane >> 4;     // k-quad / C-row quad
    u32* tb = sT[w];                // this wave's private scratch

    const int ew = blockIdx.x * TM + w * 16;     // wave's first edge

    // ---------------- gather: per-lane 32B chunks of this lane's edge row ----
    // lane (lq,ln) loads feats [kc*32+lq*8, +8) of edge ew+ln from both tables.
    // Directly lands in MFMA B-frag layout (col=edge=ln, k=kc*32+lq*8+j).
    v8s pfr[4], qfr[4], dfr[4];
    {
        int e = ew + ln; if (e >= E) e = E - 1;
        int ia = ei[e];
        int ib = ei[E + e];
        const float* prow = x_src + (size_t)ia * HID + lq * 8;
        const float* qrow = x_dst + (size_t)ib * HID + lq * 8;
        f4 pf[4][2], qf[4][2];
        #pragma unroll
        for (int kc = 0; kc < 4; ++kc) {
            const f4* pp = (const f4*)(prow + kc * 32);
            const f4* qq = (const f4*)(qrow + kc * 32);
            pf[kc][0] = pp[0]; pf[kc][1] = pp[1];
            qf[kc][0] = qq[0]; qf[kc][1] = qq[1];
        }
        #pragma unroll
        for (int kc = 0; kc < 4; ++kc)
            #pragma unroll
            for (int j = 0; j < 4; ++j) {
                pfr[kc][j]     = (short)f2b(pf[kc][0][j]);
                pfr[kc][j + 4] = (short)f2b(pf[kc][1][j]);
                qfr[kc][j]     = (short)f2b(qf[kc][0][j]);
                qfr[kc][j + 4] = (short)f2b(qf[kc][1][j]);
                dfr[kc][j]     = (short)f2b(fabsf(pf[kc][0][j] - qf[kc][0][j]));
                dfr[kc][j + 4] = (short)f2b(fabsf(pf[kc][1][j] - qf[kc][1][j]));
            }
    }

    // ---------------- stage 1: enc_p / enc_c, swapped operands ----------------
    // C[row = nt*16+lq*4+rg = outfeat, col = ln = edge]; bias+leakyrelu; pack
    // bf16 pairs to LDS [ln][fpair], read back as B-frags (k = feature).
    v8s encP[4], encC[4];
    {
        v4f acc[8];
        #pragma unroll
        for (int nt = 0; nt < 8; ++nt) acc[nt] = (v4f){0.f, 0.f, 0.f, 0.f};
        #pragma unroll
        for (int nt = 0; nt < 8; ++nt) {
            const u16* wrow = wsWp + (size_t)(nt * 16 + ln) * HID + lq * 8;
            #pragma unroll
            for (int kc = 0; kc < 4; ++kc)
                acc[nt] = MFMA(*(const v8s*)(wrow + kc * 32), pfr[kc], acc[nt]);
        }
        #pragma unroll
        for (int nt = 0; nt < 8; ++nt) {
            f4 bv = *(const f4*)(bp + nt * 16 + lq * 4);
            float v0 = acc[nt][0] + bv[0]; v0 = v0 > 0.f ? v0 : 0.01f * v0;
            float v1 = acc[nt][1] + bv[1]; v1 = v1 > 0.f ? v1 : 0.01f * v1;
            float v2 = acc[nt][2] + bv[2]; v2 = v2 > 0.f ? v2 : 0.01f * v2;
            float v3 = acc[nt][3] + bv[3]; v3 = v3 > 0.f ? v3 : 0.01f * v3;
            tb[ln * ENCS + nt * 8 + lq * 2]     = pk2(v0, v1);
            tb[ln * ENCS + nt * 8 + lq * 2 + 1] = pk2(v2, v3);
        }
        #pragma unroll
        for (int kc = 0; kc < 4; ++kc)      // feats kc*32+lq*8..+7 of edge ln
            encP[kc] = *(const v8s*)&tb[ln * ENCS + kc * 16 + lq * 4];

        // encoder C reuses acc and the same LDS region (reads above are done
        // before these writes in wave-program-order; lgkm-ordered by compiler)
        #pragma unroll
        for (int nt = 0; nt < 8; ++nt) acc[nt] = (v4f){0.f, 0.f, 0.f, 0.f};
        #pragma unroll
        for (int nt = 0; nt < 8; ++nt) {
            const u16* wrow = wsWc + (size_t)(nt * 16 + ln) * HID + lq * 8;
            #pragma unroll
            for (int kc = 0; kc < 4; ++kc)
                acc[nt] = MFMA(*(const v8s*)(wrow + kc * 32), qfr[kc], acc[nt]);
        }
        #pragma unroll
        for (int nt = 0; nt < 8; ++nt) {
            f4 bv = *(const f4*)(bc + nt * 16 + lq * 4);
            float v0 = acc[nt][0] + bv[0]; v0 = v0 > 0.f ? v0 : 0.01f * v0;
            float v1 = acc[nt][1] + bv[1]; v1 = v1 > 0.f ? v1 : 0.01f * v1;
            float v2 = acc[nt][2] + bv[2]; v2 = v2 > 0.f ? v2 : 0.01f * v2;
            float v3 = acc[nt][3] + bv[3]; v3 = v3 > 0.f ? v3 : 0.01f * v3;
            tb[ln * ENCS + nt * 8 + lq * 2]     = pk2(v0, v1);
            tb[ln * ENCS + nt * 8 + lq * 2 + 1] = pk2(v2, v3);
        }
        #pragma unroll
        for (int kc = 0; kc < 4; ++kc)
            encC[kc] = *(const v8s*)&tb[ln * ENCS + kc * 16 + lq * 4];
    }

    // ---------------- stage 2: H = relu(W1 @ EF^T + b1), K=384 ----------------
    v8s hf[4];
    {
        v4f acc[8];
        #pragma unroll
        for (int nt = 0; nt < 8; ++nt) acc[nt] = (v4f){0.f, 0.f, 0.f, 0.f};
        #pragma unroll
        for (int nt = 0; nt < 8; ++nt) {
            const u16* wrow = wsW1 + (size_t)(nt * 16 + ln) * 384 + lq * 8;
            #pragma unroll
            for (int kc = 0; kc < 4; ++kc)
                acc[nt] = MFMA(*(const v8s*)(wrow + kc * 32), encP[kc], acc[nt]);
            #pragma unroll
            for (int kc = 0; kc < 4; ++kc)
                acc[nt] = MFMA(*(const v8s*)(wrow + 128 + kc * 32), encC[kc], acc[nt]);
            #pragma unroll
            for (int kc = 0; kc < 4; ++kc)
                acc[nt] = MFMA(*(const v8s*)(wrow + 256 + kc * 32), dfr[kc], acc[nt]);
        }
        #pragma unroll
        for (int nt = 0; nt < 8; ++nt) {
            f4 bv = *(const f4*)(b1 + nt * 16 + lq * 4);
            float v0 = fmaxf(acc[nt][0] + bv[0], 0.f);
            float v1 = fmaxf(acc[nt][1] + bv[1], 0.f);
            float v2 = fmaxf(acc[nt][2] + bv[2], 0.f);
            float v3 = fmaxf(acc[nt][3] + bv[3], 0.f);
            tb[ln * ENCS + nt * 8 + lq * 2]     = pk2(v0, v1);
            tb[ln * ENCS + nt * 8 + lq * 2 + 1] = pk2(v2, v3);
        }
        #pragma unroll
        for (int kc = 0; kc < 4; ++kc)
            hf[kc] = *(const v8s*)&tb[ln * ENCS + kc * 16 + lq * 4];
    }

    // ---------------- stage 3: out = W2 @ H^T + b2 ----------------
    {
        v4f acc[8];
        #pragma unroll
        for (int nt = 0; nt < 8; ++nt) acc[nt] = (v4f){0.f, 0.f, 0.f, 0.f};
        #pragma unroll
        for (int nt = 0; nt < 8; ++nt) {
            const u16* wrow = wsW2 + (size_t)(nt * 16 + ln) * HID + lq * 8;
            #pragma unroll
            for (int kc = 0; kc < 4; ++kc)
                acc[nt] = MFMA(*(const v8s*)(wrow + kc * 32), hf[kc], acc[nt]);
        }
        // stage f32 to wave-private LDS [edge=ln][feat], then coalesced f4 store
        float* so = (float*)tb;
        #pragma unroll
        for (int nt = 0; nt < 8; ++nt) {
            f4 bv = *(const f4*)(b2 + nt * 16 + lq * 4);
            #pragma unroll
            for (int rg = 0; rg < 4; ++rg)
                so[ln * OUTS + nt * 16 + lq * 4 + rg] = acc[nt][rg] + bv[rg];
        }
        const float* sof = (const float*)tb;
        const int r  = lane >> 2;       // staged edge row 0..15
        const int cc = lane & 3;        // f4 column phase
        const int eo = ew + r;
        #pragma unroll
        for (int i = 0; i < 8; ++i) {
            f4 v = *(const f4*)&sof[r * OUTS + (cc + 4 * i) * 4];
            if (eo < E)
                *(f4*)(out + (size_t)eo * HID + (cc + 4 * i) * 4) = v;
        }
    }
}

extern "C" void kernel_launch(void* const* d_in, const int* in_sizes, int n_in,
                              void* d_out, int out_size, void* d_ws, size_t ws_size,
                              hipStream_t stream) {
    const float* x_src = (const float*)d_in[0];
    const float* x_dst = (const float*)d_in[1];
    const int*   ei    = (const int*)d_in[2];
    const float* Wp    = (const float*)d_in[3];
    const float* bp    = (const float*)d_in[4];
    const float* Wc    = (const float*)d_in[5];
    const float* bc    = (const float*)d_in[6];
    const float* W1    = (const float*)d_in[7];
    const float* b1    = (const float*)d_in[8];
    const float* W2    = (const float*)d_in[9];
    const float* b2    = (const float*)d_in[10];
    float* out = (float*)d_out;
    u16* wsW = (u16*)d_ws;                    // 98304 u16 = 196608 B

    int E = in_sizes[2] / 2;                  // edge_index is [2, E]

    cvt_weights<<<96, 256, 0, stream>>>(Wp, Wc, W1, W2, wsW);

    int blocks = (E + TM - 1) / TM;
    edge_attr_kernel<<<blocks, 256, 0, stream>>>(
        x_src, x_dst, ei, wsW, bp, bc, b1, b2, out, E);
}